// Round 1
// baseline (666.384 us; speedup 1.0000x reference)
//
#include <hip/hip_runtime.h>
#include <math.h>

// Problem constants: B=16, C=O=128, H=W=56
#define B_   16
#define C_   128
#define O_   128
#define H_   56
#define W_   56
#define HW_  3136          // H*W
#define HW4_ 784           // HW/4
#define NPC  50176.0f      // B*H*W per-channel count for BN
#define NELEM 6422528      // B*C*H*W
#define NW_  147456        // 9*O*C

// ---------------------------------------------------------------------------
// prep: LSQ-quantize both weight tensors (3-bit: clip to [-4,3], round-even)
// ---------------------------------------------------------------------------
__global__ __launch_bounds__(256) void prep_kernel(
        const float* __restrict__ w1, const float* __restrict__ wa1,
        const float* __restrict__ w2, const float* __restrict__ wa2,
        float* __restrict__ wq1, float* __restrict__ wq2) {
    int idx = blockIdx.x * 256 + threadIdx.x;        // 0 .. 2*NW_-1
    if (idx < NW_) {
        int k = idx / (O_ * C_);
        float a = wa1[k];
        wq1[idx] = rintf(fminf(fmaxf(w1[idx] / a, -4.f), 3.f)) * a;
    } else {
        int j = idx - NW_;
        int k = j / (O_ * C_);
        float a = wa2[k];
        wq2[j] = rintf(fminf(fmaxf(w2[j] / a, -4.f), 3.f)) * a;
    }
}

// ---------------------------------------------------------------------------
// conv: 9-tap split conv. Block tile = 64 pixels x 64 out-channels.
// Tap-outer loop; K (=128 in-channels) staged in LDS in chunks of 32.
// Per tap: psum accumulated fp32, then LSQ-quantized (8-bit) and accumulated.
// Thread layout: tp = tid&15 -> 4 consecutive pixels (tp*4..tp*4+3),
//                to = tid>>4 -> 4 consecutive out-channels (to*4..to*4+3).
// ---------------------------------------------------------------------------
__global__ __launch_bounds__(256) void conv_lsq_kernel(
        const float* __restrict__ xin, const float* __restrict__ wq,
        const float* __restrict__ pa, float* __restrict__ out) {
    __shared__ float xs[32][64];     // [c_chunk][pixel]
    __shared__ float wsm[32][68];    // [c_chunk][o]  (pad 68: 16B-aligned rows)

    const int tid   = threadIdx.x;
    const int ptile = blockIdx.x;          // 0..783 (64-pixel tiles; 50176/64)
    const int obase = blockIdx.y * 64;     // 0 or 64

    const int tp = tid & 15;
    const int to = tid >> 4;

    // staging pixel for this thread (one pixel, 8 channels per chunk)
    const int sp  = ptile * 64 + (tid & 63);
    const int sb  = sp / HW_;
    const int sr  = sp - sb * HW_;
    const int sh  = sr / W_;
    const int sw  = sr - sh * W_;
    const int scc = tid >> 6;              // 0..3

    // weight staging indices
    const int wcc = tid & 31;
    const int wo0 = tid >> 5;              // 0..7

    // output pixels (4 consecutive, same batch since tiles are 4-aligned)
    const int gp0 = ptile * 64 + tp * 4;
    const int ob  = gp0 / HW_;
    const int orr = gp0 - ob * HW_;

    float facc[4][4];
    #pragma unroll
    for (int i = 0; i < 4; ++i)
        #pragma unroll
        for (int j = 0; j < 4; ++j) facc[i][j] = 0.f;

    for (int k = 0; k < 9; ++k) {
        const int di = k - (k / 3) * 3 - 1;   // h shift
        const int dj = k / 3 - 1;             // w shift
        const float pak = pa[k];

        const int hh = sh + di;
        const int ww = sw + dj;
        const bool valid = (hh >= 0) && (hh < H_) && (ww >= 0) && (ww < W_);
        const int xbase = sb * (C_ * HW_) + hh * W_ + ww;
        const int wkbase = (k * O_ + obase) * C_;

        float pacc[4][4];
        #pragma unroll
        for (int i = 0; i < 4; ++i)
            #pragma unroll
            for (int j = 0; j < 4; ++j) pacc[i][j] = 0.f;

        for (int ch = 0; ch < C_; ch += 32) {
            // stage x (shifted view, zero-padded borders)
            #pragma unroll
            for (int s = 0; s < 8; ++s) {
                int cc = scc + 4 * s;
                float v = 0.f;
                if (valid) v = xin[xbase + (ch + cc) * HW_];
                xs[cc][tid & 63] = v;
            }
            // stage w transposed -> wsm[c][o]
            #pragma unroll
            for (int s = 0; s < 8; ++s) {
                int oo = wo0 + 8 * s;
                wsm[wcc][oo] = wq[wkbase + oo * C_ + ch + wcc];
            }
            __syncthreads();
            #pragma unroll
            for (int cc = 0; cc < 32; ++cc) {
                const float4 xv = *(const float4*)&xs[cc][tp * 4];
                const float4 wv = *(const float4*)&wsm[cc][to * 4];
                const float xa[4] = {xv.x, xv.y, xv.z, xv.w};
                const float wa[4] = {wv.x, wv.y, wv.z, wv.w};
                #pragma unroll
                for (int i = 0; i < 4; ++i)
                    #pragma unroll
                    for (int j = 0; j < 4; ++j)
                        pacc[i][j] = fmaf(wa[i], xa[j], pacc[i][j]);
            }
            __syncthreads();
        }

        // 8-bit LSQ quantize this tap's partial sum, accumulate
        #pragma unroll
        for (int i = 0; i < 4; ++i)
            #pragma unroll
            for (int j = 0; j < 4; ++j) {
                float q = pacc[i][j] / pak;            // exact div (match ref)
                q = fminf(fmaxf(q, -128.f), 127.f);
                facc[i][j] += rintf(q) * pak;
            }
    }

    #pragma unroll
    for (int i = 0; i < 4; ++i) {
        const int o = obase + to * 4 + i;
        float4 v = make_float4(facc[i][0], facc[i][1], facc[i][2], facc[i][3]);
        *(float4*)&out[(ob * O_ + o) * HW_ + orr] = v;
    }
}

// ---------------------------------------------------------------------------
// per-channel sum / sumsq for batch-norm stats (one block per channel)
// ---------------------------------------------------------------------------
__global__ __launch_bounds__(256) void stats_kernel(
        const float* __restrict__ in, float* __restrict__ sum_out,
        float* __restrict__ sq_out) {
    const int o = blockIdx.x;
    const float4* in4 = (const float4*)in;
    float s = 0.f, q = 0.f;
    for (int idx = threadIdx.x; idx < B_ * HW4_; idx += 256) {
        int b = idx / HW4_;
        int r = idx - b * HW4_;
        float4 v = in4[(b * O_ + o) * HW4_ + r];
        s += v.x + v.y + v.z + v.w;
        q += v.x * v.x + v.y * v.y + v.z * v.z + v.w * v.w;
    }
    #pragma unroll
    for (int off = 32; off > 0; off >>= 1) {
        s += __shfl_down(s, off, 64);
        q += __shfl_down(q, off, 64);
    }
    __shared__ float ls[4], lq[4];
    const int lane = threadIdx.x & 63, wv = threadIdx.x >> 6;
    if (lane == 0) { ls[wv] = s; lq[wv] = q; }
    __syncthreads();
    if (threadIdx.x == 0) {
        sum_out[o] = ls[0] + ls[1] + ls[2] + ls[3];
        sq_out[o]  = lq[0] + lq[1] + lq[2] + lq[3];
    }
}

// ---------------------------------------------------------------------------
// bn + relu (elementwise, float4)
// ---------------------------------------------------------------------------
__global__ __launch_bounds__(256) void bn_relu_kernel(
        const float* __restrict__ in, const float* __restrict__ sum,
        const float* __restrict__ sq, const float* __restrict__ g,
        const float* __restrict__ bb, float* __restrict__ out) {
    const int i4 = blockIdx.x * 256 + threadIdx.x;     // < NELEM/4
    const int o = (i4 / HW4_) & (O_ - 1);
    const float m   = sum[o] * (1.f / NPC);
    const float var = sq[o] * (1.f / NPC) - m * m;
    const float inv = 1.f / sqrtf(var + 1e-5f);
    const float sc = g[o] * inv;
    const float sh = bb[o] - m * sc;
    float4 v = ((const float4*)in)[i4];
    v.x = fmaxf(fmaf(v.x, sc, sh), 0.f);
    v.y = fmaxf(fmaf(v.y, sc, sh), 0.f);
    v.z = fmaxf(fmaf(v.z, sc, sh), 0.f);
    v.w = fmaxf(fmaf(v.w, sc, sh), 0.f);
    ((float4*)out)[i4] = v;
}

// ---------------------------------------------------------------------------
// bn + residual add + relu (final output)
// ---------------------------------------------------------------------------
__global__ __launch_bounds__(256) void bn_add_relu_kernel(
        const float* __restrict__ in, const float* __restrict__ sum,
        const float* __restrict__ sq, const float* __restrict__ g,
        const float* __restrict__ bb, const float* __restrict__ resid,
        float* __restrict__ out) {
    const int i4 = blockIdx.x * 256 + threadIdx.x;
    const int o = (i4 / HW4_) & (O_ - 1);
    const float m   = sum[o] * (1.f / NPC);
    const float var = sq[o] * (1.f / NPC) - m * m;
    const float inv = 1.f / sqrtf(var + 1e-5f);
    const float sc = g[o] * inv;
    const float sh = bb[o] - m * sc;
    float4 v = ((const float4*)in)[i4];
    float4 r = ((const float4*)resid)[i4];
    v.x = fmaxf(fmaf(v.x, sc, sh) + r.x, 0.f);
    v.y = fmaxf(fmaf(v.y, sc, sh) + r.y, 0.f);
    v.z = fmaxf(fmaf(v.z, sc, sh) + r.z, 0.f);
    v.w = fmaxf(fmaf(v.w, sc, sh) + r.w, 0.f);
    ((float4*)out)[i4] = v;
}

// ---------------------------------------------------------------------------
extern "C" void kernel_launch(void* const* d_in, const int* in_sizes, int n_in,
                              void* d_out, int out_size, void* d_ws, size_t ws_size,
                              hipStream_t stream) {
    const float* x   = (const float*)d_in[0];
    const float* w1  = (const float*)d_in[1];
    const float* wa1 = (const float*)d_in[2];
    const float* pa1 = (const float*)d_in[3];
    const float* g1  = (const float*)d_in[4];
    const float* b1  = (const float*)d_in[5];
    const float* w2  = (const float*)d_in[6];
    const float* wa2 = (const float*)d_in[7];
    const float* pa2 = (const float*)d_in[8];
    const float* g2  = (const float*)d_in[9];
    const float* b2  = (const float*)d_in[10];
    float* out = (float*)d_out;

    // workspace layout (floats): wq1, wq2, stats(512), bufA, bufB  (~52.6 MB)
    float* wsf   = (float*)d_ws;
    float* wq1   = wsf;
    float* wq2   = wq1 + NW_;
    float* stats = wq2 + NW_;              // sum1 | sq1 | sum2 | sq2
    float* bufA  = stats + 512;
    float* bufB  = bufA + NELEM;

    hipLaunchKernelGGL(prep_kernel, dim3(2 * NW_ / 256), dim3(256), 0, stream,
                       w1, wa1, w2, wa2, wq1, wq2);
    hipLaunchKernelGGL(conv_lsq_kernel, dim3(784, 2), dim3(256), 0, stream,
                       x, wq1, pa1, bufA);
    hipLaunchKernelGGL(stats_kernel, dim3(128), dim3(256), 0, stream,
                       bufA, stats, stats + 128);
    hipLaunchKernelGGL(bn_relu_kernel, dim3(NELEM / 4 / 256), dim3(256), 0, stream,
                       bufA, stats, stats + 128, g1, b1, bufB);
    hipLaunchKernelGGL(conv_lsq_kernel, dim3(784, 2), dim3(256), 0, stream,
                       bufB, wq2, pa2, bufA);
    hipLaunchKernelGGL(stats_kernel, dim3(128), dim3(256), 0, stream,
                       bufA, stats + 256, stats + 384);
    hipLaunchKernelGGL(bn_add_relu_kernel, dim3(NELEM / 4 / 256), dim3(256), 0, stream,
                       bufA, stats + 256, stats + 384, g2, b2, x, out);
}

// Round 2
// 228.275 us; speedup vs baseline: 2.9192x; 2.9192x over previous
//
#include <hip/hip_runtime.h>
#include <math.h>

typedef _Float16 f16;
typedef _Float16 half8 __attribute__((ext_vector_type(8)));
typedef float floatx4 __attribute__((ext_vector_type(4)));
typedef unsigned int u32;

#define B_   16
#define C_   128
#define O_   128
#define H_   56
#define W_   56
#define HW_  3136
#define NPIX 50176          // B*HW
#define NPC  50176.0f
#define NELEM 6422528
#define NW_  147456         // 9*128*128

// async 16B global->LDS copy (lane L lands at ldsbase + L*16)
typedef __attribute__((address_space(3))) u32 lds_u32;
typedef __attribute__((address_space(1))) u32 glb_u32;
__device__ __forceinline__ void async_copy16(const void* g, void* l) {
    __builtin_amdgcn_global_load_lds((const glb_u32*)g, (lds_u32*)l, 16, 0, 0);
}

// ---------------------------------------------------------------------------
// prep: w -> integer-valued fp16 weights (rint(clip(w/alpha,-4,3))), alpha NOT folded
// ---------------------------------------------------------------------------
__global__ __launch_bounds__(256) void prep_kernel(
        const float* __restrict__ w1, const float* __restrict__ wa1,
        const float* __restrict__ w2, const float* __restrict__ wa2,
        f16* __restrict__ q1, f16* __restrict__ q2) {
    int idx = blockIdx.x * 256 + threadIdx.x;    // 0..2*NW_-1
    if (idx < NW_) {
        float a = wa1[idx >> 14];
        q1[idx] = (f16)rintf(fminf(fmaxf(w1[idx] / a, -4.f), 3.f));
    } else {
        int j = idx - NW_;
        float a = wa2[j >> 14];
        q2[j] = (f16)rintf(fminf(fmaxf(w2[j] / a, -4.f), 3.f));
    }
}

// ---------------------------------------------------------------------------
// transpose+split: x fp32 [B][C][HW] -> xh/xl fp16 [B*HW][C]; also zero aux
// ---------------------------------------------------------------------------
__global__ __launch_bounds__(256) void transpose_split_kernel(
        const float* __restrict__ x, f16* __restrict__ xh, f16* __restrict__ xl,
        float* __restrict__ aux) {
    __shared__ f16 hs[64][136];
    __shared__ f16 ls[64][136];
    const int t = threadIdx.x;
    const int blk = blockIdx.x;                 // 784 tiles of 64 px
    if (blk == 0) { for (int i = t; i < 1152; i += 256) aux[i] = 0.f; }
    const int b = blk / 49;
    const int p0 = (blk - b * 49) * 64;
    #pragma unroll
    for (int i = 0; i < 8; ++i) {
        const int c = i * 16 + (t >> 4);
        const int px = (t & 15) * 4;
        const float4 v = *(const float4*)&x[((size_t)(b * C_ + c)) * HW_ + p0 + px];
        const float vv[4] = {v.x, v.y, v.z, v.w};
        #pragma unroll
        for (int j = 0; j < 4; ++j) {
            f16 h = (f16)vv[j];
            hs[px + j][c] = h;
            ls[px + j][c] = (f16)(vv[j] - (float)h);
        }
    }
    __syncthreads();
    const int px = t >> 2, seg = t & 3;
    const size_t ob = ((size_t)(b * HW_ + p0 + px)) * 128 + seg * 32;
    #pragma unroll
    for (int k = 0; k < 4; ++k) {
        *(half8*)(xh + ob + k * 8) = *(const half8*)&hs[px][seg * 32 + k * 8];
        *(half8*)(xl + ob + k * 8) = *(const half8*)&ls[px][seg * 32 + k * 8];
    }
}

// ---------------------------------------------------------------------------
// conv: 9-tap split conv, MFMA fp16 hi/lo. Block 128px x 128oc, 4 waves 64x64.
// K=256 (hi 0:128 | lo 0:128), chunks of 64: (hi,k0)(lo,k0)(hi,k1)(lo,k1).
// A double-buffered via global_load_lds; B staged once per tap.
// XOR swizzle: As slot = g ^ (row&7) (8 groups/row), Bs slot = g ^ (row&15).
// ---------------------------------------------------------------------------
__global__ __launch_bounds__(256, 2) void conv_mfma_kernel(
        const f16* __restrict__ xh, const f16* __restrict__ xl,
        const f16* __restrict__ wq, const float* __restrict__ wav,
        const float* __restrict__ pav, const f16* __restrict__ zp,
        float* __restrict__ cout, float* __restrict__ stats) {
    __shared__ f16 As[2][128][64];    // 32 KB
    __shared__ f16 Bs[128][128];      // 32 KB
    const int t = threadIdx.x;
    const int lane = t & 63;
    const int wv = t >> 6;            // 0..3
    const int wm = wv & 1, wn = wv >> 1;
    const int tile = blockIdx.x;      // 392

    // ---- per-thread staging precompute ----
    int abase_[4], ah_[4], aw_[4], gbyteA[4];
    #pragma unroll
    for (int i = 0; i < 4; ++i) {
        const int r = wv * 32 + i * 8 + (lane >> 3);
        const int gp = tile * 128 + r;
        const int b = gp / HW_;
        const int p = gp - b * HW_;
        const int h = p / W_;
        const int w = p - h * W_;
        abase_[i] = b * HW_; ah_[i] = h; aw_[i] = w;
        gbyteA[i] = (((lane & 7) ^ (r & 7)) << 4);
    }
    int boff[8];
    #pragma unroll
    for (int i = 0; i < 8; ++i) {
        const int r = wv * 32 + i * 4 + (lane >> 4);
        const int g = (lane & 15) ^ (r & 15);
        boff[i] = r * 256 + g * 16;
    }
    // ---- fragment read address precompute ----
    const int ardbase = (wm * 64 + (lane & 15)) * 128;
    const char* Bbase = (const char*)&Bs[0][0] + (wn * 64 + (lane & 15)) * 256;
    int acol[2], bcol[2][2];
    #pragma unroll
    for (int ks = 0; ks < 2; ++ks) {
        acol[ks] = (((ks * 4 + (lane >> 4)) ^ (lane & 7)) << 4);
        bcol[0][ks] = (((ks * 4 + (lane >> 4)) ^ (lane & 15)) << 4);
        bcol[1][ks] = (((8 + ks * 4 + (lane >> 4)) ^ (lane & 15)) << 4);
    }

    floatx4 acc[4][4];
    floatx4 facc[4][4];
    const floatx4 z4 = {0.f, 0.f, 0.f, 0.f};
    #pragma unroll
    for (int mt = 0; mt < 4; ++mt)
        #pragma unroll
        for (int nt = 0; nt < 4; ++nt) facc[mt][nt] = z4;

    int aoff[4];
    const char* zpc = (const char*)zp;

    auto stageA = [&](int j, int bf) {
        const char* plane = (const char*)((j & 1) ? xl : xh);
        const int khb = (j >> 1) << 7;     // 0 or 128 bytes into the 256B row
        #pragma unroll
        for (int i = 0; i < 4; ++i) {
            const char* g = (aoff[i] >= 0) ? plane + aoff[i] + khb + gbyteA[i]
                                           : zpc + gbyteA[i];
            async_copy16(g, (void*)&As[bf][wv * 32 + i * 8][0]);
        }
    };

    for (int tap = 0; tap < 9; ++tap) {
        const int di = tap - (tap / 3) * 3 - 1;   // h shift
        const int dj = tap / 3 - 1;               // w shift
        const float pak = pav[tap];
        const float s1 = wav[tap] / pak;

        #pragma unroll
        for (int i = 0; i < 4; ++i) {
            const int hp = ah_[i] + di, wp = aw_[i] + dj;
            const bool v = ((unsigned)hp < (unsigned)H_) && ((unsigned)wp < (unsigned)W_);
            aoff[i] = v ? ((abase_[i] + hp * W_ + wp) << 8) : -1;
        }
        #pragma unroll
        for (int mt = 0; mt < 4; ++mt)
            #pragma unroll
            for (int nt = 0; nt < 4; ++nt) acc[mt][nt] = z4;

        // stage B (full tap) + A chunk 0
        const char* wt = (const char*)wq + (tap << 15);
        #pragma unroll
        for (int i = 0; i < 8; ++i)
            async_copy16(wt + boff[i], (void*)&Bs[wv * 32 + i * 4][0]);
        stageA(0, 0);
        __syncthreads();

        for (int j = 0; j < 4; ++j) {
            if (j < 3) stageA(j + 1, (j + 1) & 1);
            const char* Ab = (const char*)&As[j & 1][0][0] + ardbase;
            const int kh = j >> 1;
            #pragma unroll
            for (int ks = 0; ks < 2; ++ks) {
                half8 af[4], bf4[4];
                #pragma unroll
                for (int mt = 0; mt < 4; ++mt)
                    af[mt] = *(const half8*)(Ab + mt * 2048 + acol[ks]);
                #pragma unroll
                for (int nt = 0; nt < 4; ++nt)
                    bf4[nt] = *(const half8*)(Bbase + nt * 4096 + bcol[kh][ks]);
                #pragma unroll
                for (int nt = 0; nt < 4; ++nt)
                    #pragma unroll
                    for (int mt = 0; mt < 4; ++mt)
                        acc[mt][nt] = __builtin_amdgcn_mfma_f32_16x16x32_f16(
                            af[mt], bf4[nt], acc[mt][nt], 0, 0, 0);
            }
            __syncthreads();
        }

        // 8-bit LSQ quantize partial sum, accumulate
        #pragma unroll
        for (int mt = 0; mt < 4; ++mt)
            #pragma unroll
            for (int nt = 0; nt < 4; ++nt) {
                #pragma unroll
                for (int e = 0; e < 4; ++e) {
                    float q = rintf(fminf(fmaxf(acc[mt][nt][e] * s1, -128.f), 127.f));
                    facc[mt][nt][e] = fmaf(q, pak, facc[mt][nt][e]);
                }
            }
    }

    // ---- epilogue: write cout [gp][oc] fp32 ----
    const int gp0 = tile * 128 + wm * 64;
    const int ocb = wn * 64 + (lane & 15);
    #pragma unroll
    for (int mt = 0; mt < 4; ++mt)
        #pragma unroll
        for (int e = 0; e < 4; ++e) {
            const int gp = gp0 + mt * 16 + ((lane >> 4) << 2) + e;
            float* rp = cout + (size_t)gp * 128 + ocb;
            rp[0]  = facc[mt][0][e];
            rp[16] = facc[mt][1][e];
            rp[32] = facc[mt][2][e];
            rp[48] = facc[mt][3][e];
        }

    // ---- fused BN stats: per-oc sum/sumsq over this block's 128 px ----
    float* red = (float*)&As[0][0][0];   // 1024 floats scratch
    float sv[4], qv[4];
    #pragma unroll
    for (int nt = 0; nt < 4; ++nt) {
        float s = 0.f, q = 0.f;
        #pragma unroll
        for (int mt = 0; mt < 4; ++mt)
            #pragma unroll
            for (int e = 0; e < 4; ++e) {
                const float v = facc[mt][nt][e];
                s += v; q = fmaf(v, v, q);
            }
        s += __shfl_xor(s, 16, 64); s += __shfl_xor(s, 32, 64);
        q += __shfl_xor(q, 16, 64); q += __shfl_xor(q, 32, 64);
        sv[nt] = s; qv[nt] = q;
    }
    if (lane < 16) {
        #pragma unroll
        for (int nt = 0; nt < 4; ++nt) {
            const int oc = wn * 64 + nt * 16 + lane;
            red[oc * 2 + wm] = sv[nt];
            red[512 + oc * 2 + wm] = qv[nt];
        }
    }
    __syncthreads();
    if (t < 128) {
        atomicAdd(&stats[t],       red[2 * t] + red[2 * t + 1]);
        atomicAdd(&stats[128 + t], red[512 + 2 * t] + red[512 + 2 * t + 1]);
    }
}

// ---------------------------------------------------------------------------
// bnprep: stats -> scale/shift coefficients
// ---------------------------------------------------------------------------
__global__ void bnprep_kernel(const float* __restrict__ stats,
        const float* __restrict__ g, const float* __restrict__ bb,
        float* __restrict__ coef) {
    const int t = threadIdx.x;   // 128
    const float m = stats[t] * (1.f / NPC);
    const float var = stats[128 + t] * (1.f / NPC) - m * m;
    const float inv = 1.f / sqrtf(var + 1e-5f);
    const float sc = g[t] * inv;
    coef[t] = sc;
    coef[128 + t] = bb[t] - m * sc;
}

// ---------------------------------------------------------------------------
// bn+relu+split: cout fp32 [gp][oc] -> xh/xl fp16 (conv2 input)
// ---------------------------------------------------------------------------
__global__ __launch_bounds__(256) void bn_split_kernel(
        const float* __restrict__ cin, const float* __restrict__ coef,
        f16* __restrict__ xh, f16* __restrict__ xl) {
    const int idx = blockIdx.x * 256 + threadIdx.x;    // < 802816
    const size_t base = (size_t)idx * 8;
    const int oc0 = (idx & 15) * 8;
    const float4 va = *(const float4*)(cin + base);
    const float4 vb = *(const float4*)(cin + base + 4);
    const float4 s0 = *(const float4*)(coef + oc0);
    const float4 s1 = *(const float4*)(coef + oc0 + 4);
    const float4 h0 = *(const float4*)(coef + 128 + oc0);
    const float4 h1 = *(const float4*)(coef + 128 + oc0 + 4);
    float y[8];
    y[0] = fmaxf(fmaf(va.x, s0.x, h0.x), 0.f);
    y[1] = fmaxf(fmaf(va.y, s0.y, h0.y), 0.f);
    y[2] = fmaxf(fmaf(va.z, s0.z, h0.z), 0.f);
    y[3] = fmaxf(fmaf(va.w, s0.w, h0.w), 0.f);
    y[4] = fmaxf(fmaf(vb.x, s1.x, h1.x), 0.f);
    y[5] = fmaxf(fmaf(vb.y, s1.y, h1.y), 0.f);
    y[6] = fmaxf(fmaf(vb.z, s1.z, h1.z), 0.f);
    y[7] = fmaxf(fmaf(vb.w, s1.w, h1.w), 0.f);
    half8 hv, lv;
    #pragma unroll
    for (int j = 0; j < 8; ++j) {
        f16 hh = (f16)y[j];
        hv[j] = hh;
        lv[j] = (f16)(y[j] - (float)hh);
    }
    *(half8*)(xh + base) = hv;
    *(half8*)(xl + base) = lv;
}

// ---------------------------------------------------------------------------
// final: bn2 + residual + relu, with [gp][oc] -> [b][c][p] transpose via LDS
// ---------------------------------------------------------------------------
__global__ __launch_bounds__(256) void final_kernel(
        const float* __restrict__ cin, const float* __restrict__ coef,
        const float* __restrict__ resid, float* __restrict__ out) {
    __shared__ float ts[128][68];
    const int t = threadIdx.x;
    const int blk = blockIdx.x;                 // 784
    const int b = blk / 49;
    const int p0 = (blk - b * 49) * 64;
    #pragma unroll
    for (int i = 0; i < 8; ++i) {
        const int lin = i * 256 + t;            // 0..2047
        const int px = lin >> 5;
        const int oc = (lin & 31) * 4;
        const float4 v = *(const float4*)&cin[((size_t)(b * HW_ + p0 + px)) * 128 + oc];
        const float4 sc = *(const float4*)&coef[oc];
        const float4 sh = *(const float4*)&coef[128 + oc];
        ts[oc + 0][px] = fmaf(v.x, sc.x, sh.x);
        ts[oc + 1][px] = fmaf(v.y, sc.y, sh.y);
        ts[oc + 2][px] = fmaf(v.z, sc.z, sh.z);
        ts[oc + 3][px] = fmaf(v.w, sc.w, sh.w);
    }
    __syncthreads();
    #pragma unroll
    for (int i = 0; i < 2; ++i) {
        const int c = i * 64 + (t >> 2);
        const int px = (t & 3) * 16;
        const size_t go = ((size_t)(b * C_ + c)) * HW_ + p0 + px;
        #pragma unroll
        for (int k = 0; k < 4; ++k) {
            float4 v = *(const float4*)&ts[c][px + k * 4];
            const float4 r = *(const float4*)&resid[go + k * 4];
            v.x = fmaxf(v.x + r.x, 0.f);
            v.y = fmaxf(v.y + r.y, 0.f);
            v.z = fmaxf(v.z + r.z, 0.f);
            v.w = fmaxf(v.w + r.w, 0.f);
            *(float4*)&out[go + k * 4] = v;
        }
    }
}

// ---------------------------------------------------------------------------
extern "C" void kernel_launch(void* const* d_in, const int* in_sizes, int n_in,
                              void* d_out, int out_size, void* d_ws, size_t ws_size,
                              hipStream_t stream) {
    const float* x   = (const float*)d_in[0];
    const float* w1  = (const float*)d_in[1];
    const float* wa1 = (const float*)d_in[2];
    const float* pa1 = (const float*)d_in[3];
    const float* g1  = (const float*)d_in[4];
    const float* b1  = (const float*)d_in[5];
    const float* w2  = (const float*)d_in[6];
    const float* wa2 = (const float*)d_in[7];
    const float* pa2 = (const float*)d_in[8];
    const float* g2  = (const float*)d_in[9];
    const float* b2  = (const float*)d_in[10];
    float* out = (float*)d_out;

    // ws layout (bytes): xh 12845056 | xl 12845056 | wq1 294912 | wq2 294912 |
    //                    cout 25690112 | aux 4608   (total ~52.0 MB)
    char* ws = (char*)d_ws;
    f16* xh  = (f16*)ws;
    f16* xl  = (f16*)(ws + 12845056);
    f16* wq1 = (f16*)(ws + 25690112);
    f16* wq2 = (f16*)(ws + 25690112 + 294912);
    float* cbuf = (float*)(ws + 25690112 + 2 * 294912);
    float* aux  = (float*)(ws + 25690112 + 2 * 294912 + 25690112);
    // aux: [0,256) stats1 | [256,512) stats2 | [512,768) coef1 | [768,1024) coef2 | [1024,1152) zero page
    float* stats1 = aux;
    float* stats2 = aux + 256;
    float* coef1  = aux + 512;
    float* coef2  = aux + 768;
    const f16* zp = (const f16*)(aux + 1024);

    hipLaunchKernelGGL(prep_kernel, dim3(1152), dim3(256), 0, stream,
                       w1, wa1, w2, wa2, wq1, wq2);
    hipLaunchKernelGGL(transpose_split_kernel, dim3(784), dim3(256), 0, stream,
                       x, xh, xl, aux);
    hipLaunchKernelGGL(conv_mfma_kernel, dim3(392), dim3(256), 0, stream,
                       xh, xl, wq1, wa1, pa1, zp, cbuf, stats1);
    hipLaunchKernelGGL(bnprep_kernel, dim3(1), dim3(128), 0, stream,
                       stats1, g1, b1, coef1);
    hipLaunchKernelGGL(bn_split_kernel, dim3(3136), dim3(256), 0, stream,
                       cbuf, coef1, xh, xl);
    hipLaunchKernelGGL(conv_mfma_kernel, dim3(392), dim3(256), 0, stream,
                       xh, xl, wq2, wa2, pa2, zp, cbuf, stats2);
    hipLaunchKernelGGL(bnprep_kernel, dim3(1), dim3(128), 0, stream,
                       stats2, g2, b2, coef2);
    hipLaunchKernelGGL(final_kernel, dim3(784), dim3(256), 0, stream,
                       cbuf, coef2, x, out);
}